// Round 9
// baseline (499.813 us; speedup 1.0000x reference)
//
#include <hip/hip_runtime.h>

typedef __attribute__((ext_vector_type(4))) float f32x4;
typedef __attribute__((ext_vector_type(4))) int   i32x4;

static constexpr int Kd = 4096, Nd = 16384, Md = 1024;
static constexpr int BK = 128;          // K-elems (i8) per tile
static constexpr int NT = Kd / BK;      // 32 K-tiles
static constexpr int BM = 128, BN = 256;

// ---------- helpers ----------

__device__ __forceinline__ void gload16(const char* g, char* l) {
    __builtin_amdgcn_global_load_lds(
        (const __attribute__((address_space(1))) void*)g,
        (__attribute__((address_space(3))) void*)l, 16, 0, 0);
}

__device__ __forceinline__ int pack4(int a, int b, int c, int d) {
    return (a & 255) | ((b & 255) << 8) | ((c & 255) << 16) | (d << 24);
}

// ---------- convert X: f32 [M][K] -> per-row absmax-scaled int8 ----------

__global__ __launch_bounds__(256) void convert_x_kernel(
    const float* __restrict__ x, char* __restrict__ xb, float* __restrict__ xs) {
    const int row = blockIdx.x;
    const int t   = threadIdx.x;
    const float* xr = x + (size_t)row * Kd;

    f32x4 v[4];
    float amax = 0.f;
    #pragma unroll
    for (int i = 0; i < 4; ++i) {
        v[i] = *(const f32x4*)(xr + t * 16 + i * 4);
        #pragma unroll
        for (int j = 0; j < 4; ++j) amax = fmaxf(amax, fabsf(v[i][j]));
    }
    #pragma unroll
    for (int off = 32; off; off >>= 1)
        amax = fmaxf(amax, __shfl_xor(amax, off));
    __shared__ float wmax[4];
    if ((t & 63) == 0) wmax[t >> 6] = amax;
    __syncthreads();
    amax = fmaxf(fmaxf(wmax[0], wmax[1]), fmaxf(wmax[2], wmax[3]));
    amax = fmaxf(amax, 1e-20f);

    const float inv = 127.0f / amax;
    i32x4 o;
    #pragma unroll
    for (int i = 0; i < 4; ++i) {
        int q[4];
        #pragma unroll
        for (int j = 0; j < 4; ++j) {
            int qi = __float2int_rn(v[i][j] * inv);
            qi = qi > 127 ? 127 : (qi < -127 ? -127 : qi);
            q[j] = qi;
        }
        o[i] = pack4(q[0], q[1], q[2], q[3]);
    }
    *(i32x4*)(xb + (size_t)row * Kd + t * 16) = o;
    if (t == 0) xs[row] = amax * (1.0f / 127.0f);
}

// ---------- fused 128x256 i8 GEMM, 512 thr / 8 waves / 2 waves-per-SIMD ----------
// C[m,n] = sw[n]*xs[m] * sum_k xq[m,k]*w8[n,k] + bias[n],  w8 = low byte of Wq
// 8 waves = 2M x 4N; per-wave out 64x64 (acc 64 regs). Register budget/wave:
// acc 64 + af 32 + raw 64 + bfp 32 + addr ~20 = ~215 <= 256 -> 2 waves/SIMD
// (r7 lesson: no spill; r8 lesson: must have TLP).
// A: i8 via LDS, 2 slots x 16 KiB, XOR swizzle, gload_lds (2 ops/thread/tile).
// B: raw int32 -> regs in two 16-load halves (ni{0,1} / ni{2,3}), packed
// in-reg (pack4); bh1 prefetched one tile ahead. One barrier per tile.
// Per-tile ledger (FIFO oldest-left, waits audited incl. prologue/tail):
//  entry [bh1(t):16] ; VMCNT(0)->pack bfp[2..3] ; LOAD bh0(t) [bh0:16] ;
//  STAGE_A(t+1) [bh0:16,A:2] ; LGKM(0) ; G(ni 2,3) 16 MFMA ;
//  VMCNT(2)->bh0 done, pack bfp[0..1] ; LOAD bh1(t+1) [A:2,bh1:16] ;
//  G(ni 0,1) 16 MFMA ; VMCNT(16)->A(t+1) done ; BARRIER.

#define BARRIER() asm volatile("s_barrier" ::: "memory")

#define LGKM(n) do {                                                           \
    asm volatile("s_waitcnt lgkmcnt(" #n ")" ::: "memory");                    \
    __builtin_amdgcn_sched_barrier(0);                                         \
} while (0)

#define VMCNT(n) do {                                                          \
    asm volatile("s_waitcnt vmcnt(" #n ")" ::: "memory");                      \
    __builtin_amdgcn_sched_barrier(0);                                         \
} while (0)

// stage full A tile (128 rows x 128 B) for kt into slot: 2 gload_lds/thread
#define STAGE_A2(slot, kt) do {                                                \
    _Pragma("unroll")                                                          \
    for (int i_ = 0; i_ < 2; ++i_) {                                           \
        char* lb_ = &LDSA[slot][i_ * 64 + w * 8][0];                           \
        gload16(Ab + (aRow0 + i_ * 64) * (size_t)Kd + (kt) * BK + gcol, lb_);  \
    }                                                                          \
    __builtin_amdgcn_sched_barrier(0);                                         \
} while (0)

// issue 16 dwordx4 raw int32 loads for B-half (half=0: ni{0,1}; 1: ni{2,3})
#define LOAD_BH(half, kt) do {                                                 \
    _Pragma("unroll")                                                          \
    for (int n2 = 0; n2 < 2; ++n2)                                             \
        _Pragma("unroll")                                                      \
        for (int kk = 0; kk < 2; ++kk) {                                       \
            const int off_ = bOff0 + ((half) * 2 + n2) * 16 * Kd               \
                             + (kt) * BK + kk * 64;                            \
            _Pragma("unroll")                                                  \
            for (int i = 0; i < 4; ++i)                                        \
                raw[n2][kk][i] = *(const i32x4*)(bBase + off_ + i * 4);        \
        }                                                                      \
    __builtin_amdgcn_sched_barrier(0);                                         \
} while (0)

#define PACK_BH(half) do {                                                     \
    _Pragma("unroll")                                                          \
    for (int n2 = 0; n2 < 2; ++n2)                                             \
        _Pragma("unroll")                                                      \
        for (int kk = 0; kk < 2; ++kk)                                         \
            _Pragma("unroll")                                                  \
            for (int i = 0; i < 4; ++i)                                        \
                bfp[(half) * 2 + n2][kk][i] =                                  \
                    pack4(raw[n2][kk][i][0], raw[n2][kk][i][1],                \
                          raw[n2][kk][i][2], raw[n2][kk][i][3]);               \
} while (0)

// 8 ds_read_b128 -> af[4][2]
#define READ_A8(slot) do {                                                     \
    const char* lA_ = &LDSA[slot][0][0];                                       \
    _Pragma("unroll")                                                          \
    for (int mi = 0; mi < 4; ++mi)                                             \
        _Pragma("unroll")                                                      \
        for (int kk = 0; kk < 2; ++kk) {                                       \
            const int row_ = wm * 64 + mi * 16 + lr;                           \
            const int col_ = (l4 * 16 + kk * 64) ^ xorv;                       \
            af[mi][kk] = *(const i32x4*)(lA_ + row_ * 128 + col_);             \
        }                                                                      \
    __builtin_amdgcn_sched_barrier(0);                                         \
} while (0)

// 16 MFMA: mi 0..3 x ni {nlo, nlo+1} x kk 0..1
#define MFMA_G(nlo) do {                                                       \
    __builtin_amdgcn_s_setprio(1);                                             \
    _Pragma("unroll")                                                          \
    for (int mi = 0; mi < 4; ++mi)                                             \
        _Pragma("unroll")                                                      \
        for (int n2 = 0; n2 < 2; ++n2)                                         \
            _Pragma("unroll")                                                  \
            for (int kk = 0; kk < 2; ++kk)                                     \
                acc[mi][(nlo) + n2] =                                          \
                    __builtin_amdgcn_mfma_i32_16x16x64_i8(                     \
                        af[mi][kk], bfp[(nlo) + n2][kk],                       \
                        acc[mi][(nlo) + n2], 0, 0, 0);                         \
    __builtin_amdgcn_s_setprio(0);                                             \
} while (0)

#define TILE(slot, oslot, t) do {                                              \
    READ_A8(slot);                     /* 8 ds_read_b128 */                    \
    VMCNT(0);                          /* bh1(t) done (only thing in flight) */\
    PACK_BH(1);                        /* bfp[2..3] */                         \
    LOAD_BH(0, t);                     /* [bh0:16] */                          \
    if ((t) + 1 < NT) STAGE_A2(oslot, (t) + 1);   /* [bh0:16, A:2] */          \
    LGKM(0);                           /* af ready */                          \
    MFMA_G(2);                         /* 16 MFMA, covers bh0 latency */       \
    if ((t) + 1 < NT) { VMCNT(2); } else { VMCNT(0); }  /* bh0 done */         \
    PACK_BH(0);                        /* bfp[0..1] */                         \
    if ((t) + 1 < NT) LOAD_BH(1, (t) + 1);        /* [A:2, bh1:16] */          \
    MFMA_G(0);                         /* 16 MFMA, covers bh1 latency */       \
    if ((t) + 1 < NT) { VMCNT(16); BARRIER(); }   /* A(t+1) done */            \
} while (0)

__global__ __launch_bounds__(512, 2) void gemm8f_kernel(
    const char* __restrict__ Ab,        // xq [M][K] i8
    const int*  __restrict__ Wq,        // weight_quant [N][K] int32 (raw input)
    const float* __restrict__ sw,       // per-n weight scale
    const float* __restrict__ xs,       // per-m activation scale
    const float* __restrict__ bias,
    float* __restrict__ C) {

    __shared__ __align__(16) char LDSA[2][128][128];   // 32 KiB, A only

    const int tid = threadIdx.x;
    const int l   = tid & 63;
    const int w   = tid >> 6;          // wave 0..7
    const int wm  = w >> 2;            // 0..1 (m half, 64 rows)
    const int wn  = w & 3;             // 0..3 (n quarter, 64 cols)
    const int lr  = l & 15;
    const int l4  = l >> 4;            // 0..3
    const int xorv = (lr & 7) << 4;

    // bijective XCD swizzle (512 wg, 64/XCD), m-fastest: the 8 m-blocks
    // sharing an n-panel land on one XCD -> B re-reads are L2 hits
    const int orig = blockIdx.x;
    const int work = (orig & 7) * 64 + (orig >> 3);
    const int gm0 = (work & 7) * BM;
    const int gn0 = (work >> 3) * BN;

    // A staging source geometry (inverse of read-side XOR swizzle), bytes
    const int g_log = (l & 7) ^ ((l >> 3) & 7);
    const int gcol  = g_log * 16;
    const size_t aRow0 = (size_t)(gm0 + w * 8 + (l >> 3));

    // B raw int32 addressing: uniform base + per-lane offset (dword units)
    const int* bBase = Wq + (size_t)gn0 * Kd;
    const int  bOff0 = (wn * 64 + lr) * Kd + l4 * 16;

    i32x4 af[4][2];                    // A frags, 32 regs
    i32x4 raw[2][2][4];                // raw int32 B-half buffer, 64 regs
    i32x4 bfp[4][2];                   // packed i8 B frags (ni 0..3), 32 regs

    i32x4 acc[4][4];                   // 64 regs
    #pragma unroll
    for (int i = 0; i < 4; ++i)
        #pragma unroll
        for (int j = 0; j < 4; ++j) {
            i32x4 z = {0, 0, 0, 0};
            acc[i][j] = z;
        }

    // prologue: A(0) staged, bh1(0) issued
    STAGE_A2(0, 0);                    // [A:2]
    LOAD_BH(1, 0);                     // [A:2, bh1:16]
    VMCNT(16);                         // A(0) done; bh1 stays in flight
    BARRIER();

    #pragma unroll 1
    for (int tt = 0; tt < NT / 2; ++tt) {
        TILE(0, 1, 2 * tt);
        TILE(1, 0, 2 * tt + 1);
    }

    // epilogue: C = sw[n]*xs[m]*acc + bias[n]
    // C/D layout (dtype-independent): col = lane&15 (n), row = (lane>>4)*4+reg
    #pragma unroll
    for (int bj = 0; bj < 4; ++bj) {
        const int gn = gn0 + wn * 64 + bj * 16 + lr;
        const float sc = sw[gn];
        const float bi = bias[gn];
        #pragma unroll
        for (int ai = 0; ai < 4; ++ai) {
            const int gm = gm0 + wm * 64 + ai * 16 + l4 * 4;
            #pragma unroll
            for (int r = 0; r < 4; ++r)
                C[(size_t)(gm + r) * Nd + gn] =
                    (float)acc[ai][bj][r] * (sc * xs[gm + r]) + bi;
        }
    }
}

// ---------- fallback (ws too small): slow but correct ----------

__global__ __launch_bounds__(256) void naive_kernel(
    const float* __restrict__ x, const int* __restrict__ wq,
    const float* __restrict__ scale, const float* __restrict__ bias,
    float* __restrict__ out) {
    const int n = blockIdx.x * 256 + threadIdx.x;
    const int m = blockIdx.y;
    if (n >= Nd) return;
    const float* xr = x + (size_t)m * Kd;
    const int*   wr = wq + (size_t)n * Kd;
    float s = 0.f;
    for (int k = 0; k < Kd; ++k) s += xr[k] * (float)wr[k];
    out[(size_t)m * Nd + n] = s * scale[n] + bias[n];
}

// ---------- launch ----------

extern "C" void kernel_launch(void* const* d_in, const int* in_sizes, int n_in,
                              void* d_out, int out_size, void* d_ws, size_t ws_size,
                              hipStream_t stream) {
    const float* x     = (const float*)d_in[0];
    const int*   wq    = (const int*)d_in[1];
    const float* scale = (const float*)d_in[2];
    const float* bias  = (const float*)d_in[3];
    float* out = (float*)d_out;

    const size_t x_bytes = (size_t)Md * Kd;              // 4 MiB (i8)
    const size_t s_bytes = (size_t)Md * sizeof(float);   // 4 KiB
    if (ws_size >= x_bytes + s_bytes && d_ws != nullptr) {
        char*  xb = (char*)d_ws;
        float* xs = (float*)(xb + x_bytes);
        convert_x_kernel<<<Md, 256, 0, stream>>>(x, xb, xs);
        const int nwg = (Md / BM) * (Nd / BN);           // 512
        gemm8f_kernel<<<nwg, 512, 0, stream>>>(xb, wq, scale, xs, bias, out);
    } else {
        dim3 grid(Nd / 256, Md);
        naive_kernel<<<grid, 256, 0, stream>>>(x, wq, scale, bias, out);
    }
}

// Round 10
// 228.133 us; speedup vs baseline: 2.1909x; 2.1909x over previous
//
#include <hip/hip_runtime.h>

typedef __attribute__((ext_vector_type(4))) float f32x4;
typedef __attribute__((ext_vector_type(4))) int   i32x4;

static constexpr int Kd = 4096, Nd = 16384, Md = 1024;
static constexpr int BK = 128;          // K-elems (i8) per tile
static constexpr int NT = Kd / BK;      // 32 K-tiles
static constexpr int BM = 128, BN = 256;

// ---------- helpers ----------

__device__ __forceinline__ void gload16(const char* g, char* l) {
    __builtin_amdgcn_global_load_lds(
        (const __attribute__((address_space(1))) void*)g,
        (__attribute__((address_space(3))) void*)l, 16, 0, 0);
}

__device__ __forceinline__ int pack4(int a, int b, int c, int d) {
    return (a & 255) | ((b & 255) << 8) | ((c & 255) << 16) | (d << 24);
}

// ---------- convert W: int32 [N][K] -> i8 [N][K] linear (exact, BW-floor) ----------

__global__ __launch_bounds__(256) void convert_w_kernel(
    const int* __restrict__ wq, char* __restrict__ wb) {
    const int ngroups = (Nd / 16) * Kd;      // groups of 16 elems
    int g = blockIdx.x * 256 + threadIdx.x;
    const int stride = gridDim.x * 256;
    for (; g < ngroups; g += stride) {
        const int* src = wq + (size_t)g * 16;
        i32x4 a = *(const i32x4*)(src);
        i32x4 b = *(const i32x4*)(src + 4);
        i32x4 c = *(const i32x4*)(src + 8);
        i32x4 d = *(const i32x4*)(src + 12);
        i32x4 o;
        o[0] = pack4(a[0], a[1], a[2], a[3]);
        o[1] = pack4(b[0], b[1], b[2], b[3]);
        o[2] = pack4(c[0], c[1], c[2], c[3]);
        o[3] = pack4(d[0], d[1], d[2], d[3]);
        *(i32x4*)(wb + (size_t)g * 16) = o;
    }
}

// ---------- convert X: f32 [M][K] -> per-row absmax-scaled int8 ----------

__global__ __launch_bounds__(256) void convert_x_kernel(
    const float* __restrict__ x, char* __restrict__ xb, float* __restrict__ xs) {
    const int row = blockIdx.x;
    const int t   = threadIdx.x;
    const float* xr = x + (size_t)row * Kd;

    f32x4 v[4];
    float amax = 0.f;
    #pragma unroll
    for (int i = 0; i < 4; ++i) {
        v[i] = *(const f32x4*)(xr + t * 16 + i * 4);
        #pragma unroll
        for (int j = 0; j < 4; ++j) amax = fmaxf(amax, fabsf(v[i][j]));
    }
    #pragma unroll
    for (int off = 32; off; off >>= 1)
        amax = fmaxf(amax, __shfl_xor(amax, off));
    __shared__ float wmax[4];
    if ((t & 63) == 0) wmax[t >> 6] = amax;
    __syncthreads();
    amax = fmaxf(fmaxf(wmax[0], wmax[1]), fmaxf(wmax[2], wmax[3]));
    amax = fmaxf(amax, 1e-20f);

    const float inv = 127.0f / amax;
    i32x4 o;
    #pragma unroll
    for (int i = 0; i < 4; ++i) {
        int q[4];
        #pragma unroll
        for (int j = 0; j < 4; ++j) {
            int qi = __float2int_rn(v[i][j] * inv);
            qi = qi > 127 ? 127 : (qi < -127 ? -127 : qi);
            q[j] = qi;
        }
        o[i] = pack4(q[0], q[1], q[2], q[3]);
    }
    *(i32x4*)(xb + (size_t)row * Kd + t * 16) = o;
    if (t == 0) xs[row] = amax * (1.0f / 127.0f);
}

// ---------- 128x256 i8 GEMM: A via LDS, B i8 frag-direct, 1 barrier/tile ----------
// C[m,n] = sw[n]*xs[m] * sum_k xq[m,k]*w8[n,k] + bias[n]
// 8 waves = 2M x 4N; per-wave out 64x64 (acc 64). Regs: acc 64 + af 32 +
// bfC 32 + bfN 32 + addr ~20 = ~180 <= 256 -> 2 waves/SIMD, no spill.
// A: i8 via LDS (2 slots x 16 KiB, XOR swizzle, gload_lds, 2/thread/tile).
// B: i8 frags loaded one tile ahead straight into regs (8 dwordx4/wave/tile)
// from the 1 MB L2-resident n-panel (B traffic 64 KB/CU/tile ~ 600 cyc).
// Per-tile ledger (FIFO oldest-left; vmcnt retires in issue order, m135):
//  entry [B(t):8] ; READ_A8 (8 ds) ; STAGE_A(t+1) [B:8,A:4] ;
//  LOAD_B(t+1)->bfN [B:8,A:4,B':8]=20 ; VMCNT(12) -> B(t) done ;
//  LGKM(0) -> af ready ; 32 MFMA ; VMCNT(8) -> A(t+1) done ; BARRIER.
// Tail (t=NT-1): no stage/load, VMCNT(0), no barrier.

#define BARRIER() asm volatile("s_barrier" ::: "memory")

#define LGKM(n) do {                                                           \
    asm volatile("s_waitcnt lgkmcnt(" #n ")" ::: "memory");                    \
    __builtin_amdgcn_sched_barrier(0);                                         \
} while (0)

#define VMCNT(n) do {                                                          \
    asm volatile("s_waitcnt vmcnt(" #n ")" ::: "memory");                      \
    __builtin_amdgcn_sched_barrier(0);                                         \
} while (0)

// stage full A tile (128 rows x 128 B) for kt into slot: 2 gload_lds/thread
#define STAGE_A2(slot, kt) do {                                                \
    _Pragma("unroll")                                                          \
    for (int i_ = 0; i_ < 2; ++i_) {                                           \
        char* lb_ = &LDSA[slot][i_ * 64 + w * 8][0];                           \
        gload16(Ab + (aRow0 + i_ * 64) * (size_t)Kd + (kt) * BK + gcol, lb_);  \
    }                                                                          \
    __builtin_amdgcn_sched_barrier(0);                                         \
} while (0)

// 8 dwordx4: i8 B frags (nj 0..3, kk 0..1) for tile kt -> buf
#define LOAD_B8(buf, kt) do {                                                  \
    _Pragma("unroll")                                                          \
    for (int nj = 0; nj < 4; ++nj)                                             \
        _Pragma("unroll")                                                      \
        for (int kk = 0; kk < 2; ++kk)                                         \
            buf[nj][kk] = *(const i32x4*)(bB + (size_t)nj * 16 * Kd            \
                                          + (kt) * BK + kk * 64);              \
    __builtin_amdgcn_sched_barrier(0);                                         \
} while (0)

// 8 ds_read_b128 -> af[4][2]
#define READ_A8(slot) do {                                                     \
    const char* lA_ = &LDSA[slot][0][0];                                       \
    _Pragma("unroll")                                                          \
    for (int mi = 0; mi < 4; ++mi)                                             \
        _Pragma("unroll")                                                      \
        for (int kk = 0; kk < 2; ++kk) {                                       \
            const int row_ = wm * 64 + mi * 16 + lr;                           \
            const int col_ = (l4 * 16 + kk * 64) ^ xorv;                       \
            af[mi][kk] = *(const i32x4*)(lA_ + row_ * 128 + col_);             \
        }                                                                      \
    __builtin_amdgcn_sched_barrier(0);                                         \
} while (0)

// 32 MFMA: mi 0..3 x nj 0..3 x kk 0..1
#define MFMA32(BF) do {                                                        \
    __builtin_amdgcn_s_setprio(1);                                             \
    _Pragma("unroll")                                                          \
    for (int mi = 0; mi < 4; ++mi)                                             \
        _Pragma("unroll")                                                      \
        for (int nj = 0; nj < 4; ++nj)                                         \
            _Pragma("unroll")                                                  \
            for (int kk = 0; kk < 2; ++kk)                                     \
                acc[mi][nj] = __builtin_amdgcn_mfma_i32_16x16x64_i8(           \
                    af[mi][kk], BF[nj][kk], acc[mi][nj], 0, 0, 0);             \
    __builtin_amdgcn_s_setprio(0);                                             \
} while (0)

#define TILE(slot, oslot, BFC, BFN, t) do {                                    \
    READ_A8(slot);                                                             \
    if ((t) + 1 < NT) {                                                        \
        STAGE_A2(oslot, (t) + 1);      /* [B:8, A:4] */                        \
        LOAD_B8(BFN, (t) + 1);         /* [B:8, A:4, B':8] */                  \
        VMCNT(12);                     /* B(t) regs ready */                   \
    } else {                                                                   \
        VMCNT(0);                                                              \
    }                                                                          \
    LGKM(0);                           /* af ready */                          \
    MFMA32(BFC);                                                               \
    if ((t) + 1 < NT) { VMCNT(8); BARRIER(); }   /* A(t+1) in LDS */           \
} while (0)

__global__ __launch_bounds__(512, 2) void gemm8_kernel(
    const char* __restrict__ Ab,        // xq [M][K] i8
    const char* __restrict__ Bw,        // w8 [N][K] i8 (linear)
    const float* __restrict__ sw,       // per-n weight scale
    const float* __restrict__ xs,       // per-m activation scale
    const float* __restrict__ bias,
    float* __restrict__ C) {

    __shared__ __align__(16) char LDSA[2][128][128];   // 32 KiB, A only

    const int tid = threadIdx.x;
    const int l   = tid & 63;
    const int w   = tid >> 6;          // wave 0..7
    const int wm  = w >> 2;            // 0..1 (m half, 64 rows)
    const int wn  = w & 3;             // 0..3 (n quarter, 64 cols)
    const int lr  = l & 15;
    const int l4  = l >> 4;            // 0..3
    const int xorv = (lr & 7) << 4;

    // bijective XCD swizzle (512 wg, 64/XCD), m-fastest: blocks sharing an
    // n-panel co-resident per XCD -> 1 MB i8 panel L2-resident
    const int orig = blockIdx.x;
    const int work = (orig & 7) * 64 + (orig >> 3);
    const int gm0 = (work & 7) * BM;
    const int gn0 = (work >> 3) * BN;

    // A staging source geometry (inverse of read-side XOR swizzle), bytes
    const int g_log = (l & 7) ^ ((l >> 3) & 7);
    const int gcol  = g_log * 16;
    const size_t aRow0 = (size_t)(gm0 + w * 8 + (l >> 3));

    // B i8 frag-direct base: rows gn0 + wn*64 + nj*16 + lr, 16 B at l4*16
    const char* bB = Bw + (size_t)(gn0 + wn * 64 + lr) * Kd + l4 * 16;

    i32x4 af[4][2];                    // A frags, 32 regs
    i32x4 bfA[4][2], bfB[4][2];        // B i8 frag dbuf, 32+32 regs

    i32x4 acc[4][4];                   // 64 regs
    #pragma unroll
    for (int i = 0; i < 4; ++i)
        #pragma unroll
        for (int j = 0; j < 4; ++j) {
            i32x4 z = {0, 0, 0, 0};
            acc[i][j] = z;
        }

    // prologue: A(0) staged, B(0) issued
    STAGE_A2(0, 0);                    // [A:4]
    LOAD_B8(bfA, 0);                   // [A:4, B:8]
    VMCNT(8);                          // A(0) done; B stays in flight
    BARRIER();

    #pragma unroll 1
    for (int tt = 0; tt < NT / 2; ++tt) {
        TILE(0, 1, bfA, bfB, 2 * tt);
        TILE(1, 0, bfB, bfA, 2 * tt + 1);
    }

    // epilogue: C = sw[n]*xs[m]*acc + bias[n]
    // C/D layout (dtype-independent): col = lane&15 (n), row = (lane>>4)*4+reg
    #pragma unroll
    for (int bj = 0; bj < 4; ++bj) {
        const int gn = gn0 + wn * 64 + bj * 16 + lr;
        const float sc = sw[gn];
        const float bi = bias[gn];
        #pragma unroll
        for (int ai = 0; ai < 4; ++ai) {
            const int gm = gm0 + wm * 64 + ai * 16 + l4 * 4;
            #pragma unroll
            for (int r = 0; r < 4; ++r)
                C[(size_t)(gm + r) * Nd + gn] =
                    (float)acc[ai][bj][r] * (sc * xs[gm + r]) + bi;
        }
    }
}

// ---------- fallback (ws too small): slow but correct ----------

__global__ __launch_bounds__(256) void naive_kernel(
    const float* __restrict__ x, const int* __restrict__ wq,
    const float* __restrict__ scale, const float* __restrict__ bias,
    float* __restrict__ out) {
    const int n = blockIdx.x * 256 + threadIdx.x;
    const int m = blockIdx.y;
    if (n >= Nd) return;
    const float* xr = x + (size_t)m * Kd;
    const int*   wr = wq + (size_t)n * Kd;
    float s = 0.f;
    for (int k = 0; k < Kd; ++k) s += xr[k] * (float)wr[k];
    out[(size_t)m * Nd + n] = s * scale[n] + bias[n];
}

// ---------- launch ----------

extern "C" void kernel_launch(void* const* d_in, const int* in_sizes, int n_in,
                              void* d_out, int out_size, void* d_ws, size_t ws_size,
                              hipStream_t stream) {
    const float* x     = (const float*)d_in[0];
    const int*   wq    = (const int*)d_in[1];
    const float* scale = (const float*)d_in[2];
    const float* bias  = (const float*)d_in[3];
    float* out = (float*)d_out;

    const size_t w_bytes = (size_t)Nd * Kd;              // 64 MiB (i8)
    const size_t x_bytes = (size_t)Md * Kd;              //  4 MiB (i8)
    const size_t s_bytes = (size_t)Md * sizeof(float);   //  4 KiB
    if (ws_size >= w_bytes + x_bytes + s_bytes && d_ws != nullptr) {
        char*  wb = (char*)d_ws;
        char*  xb = wb + w_bytes;
        float* xs = (float*)(xb + x_bytes);
        convert_w_kernel<<<4096, 256, 0, stream>>>(wq, wb);
        convert_x_kernel<<<Md, 256, 0, stream>>>(x, xb, xs);
        const int nwg = (Md / BM) * (Nd / BN);           // 512
        gemm8_kernel<<<nwg, 512, 0, stream>>>(xb, wb, scale, xs, bias, out);
    } else {
        dim3 grid(Nd / 256, Md);
        naive_kernel<<<grid, 256, 0, stream>>>(x, wq, scale, bias, out);
    }
}

// Round 11
// 172.748 us; speedup vs baseline: 2.8933x; 1.3206x over previous
//
#include <hip/hip_runtime.h>

typedef __attribute__((ext_vector_type(4))) float f32x4;
typedef __attribute__((ext_vector_type(4))) int   i32x4;

static constexpr int Kd = 4096, Nd = 16384, Md = 1024;
static constexpr int BK = 128;          // K-elems (i8) per tile
static constexpr int NT = Kd / BK;      // 32 K-tiles

// ---------- helpers ----------

__device__ __forceinline__ int pack4(int a, int b, int c, int d) {
    return (a & 255) | ((b & 255) << 8) | ((c & 255) << 16) | (d << 24);
}

// ---------- convert W: int32 [N][K] -> i8 [N][K] linear (exact, BW-floor) ----------

__global__ __launch_bounds__(256) void convert_w_kernel(
    const int* __restrict__ wq, char* __restrict__ wb) {
    const int ngroups = (Nd / 16) * Kd;
    int g = blockIdx.x * 256 + threadIdx.x;
    const int stride = gridDim.x * 256;
    for (; g < ngroups; g += stride) {
        const int* src = wq + (size_t)g * 16;
        i32x4 a = *(const i32x4*)(src);
        i32x4 b = *(const i32x4*)(src + 4);
        i32x4 c = *(const i32x4*)(src + 8);
        i32x4 d = *(const i32x4*)(src + 12);
        i32x4 o;
        o[0] = pack4(a[0], a[1], a[2], a[3]);
        o[1] = pack4(b[0], b[1], b[2], b[3]);
        o[2] = pack4(c[0], c[1], c[2], c[3]);
        o[3] = pack4(d[0], d[1], d[2], d[3]);
        *(i32x4*)(wb + (size_t)g * 16) = o;
    }
}

// ---------- convert X: f32 [M][K] -> per-row absmax-scaled int8 ----------

__global__ __launch_bounds__(256) void convert_x_kernel(
    const float* __restrict__ x, char* __restrict__ xb, float* __restrict__ xs) {
    const int row = blockIdx.x;
    const int t   = threadIdx.x;
    const float* xr = x + (size_t)row * Kd;

    f32x4 v[4];
    float amax = 0.f;
    #pragma unroll
    for (int i = 0; i < 4; ++i) {
        v[i] = *(const f32x4*)(xr + t * 16 + i * 4);
        #pragma unroll
        for (int j = 0; j < 4; ++j) amax = fmaxf(amax, fabsf(v[i][j]));
    }
    #pragma unroll
    for (int off = 32; off; off >>= 1)
        amax = fmaxf(amax, __shfl_xor(amax, off));
    __shared__ float wmax[4];
    if ((t & 63) == 0) wmax[t >> 6] = amax;
    __syncthreads();
    amax = fmaxf(fmaxf(wmax[0], wmax[1]), fmaxf(wmax[2], wmax[3]));
    amax = fmaxf(amax, 1e-20f);

    const float inv = 127.0f / amax;
    i32x4 o;
    #pragma unroll
    for (int i = 0; i < 4; ++i) {
        int q[4];
        #pragma unroll
        for (int j = 0; j < 4; ++j) {
            int qi = __float2int_rn(v[i][j] * inv);
            qi = qi > 127 ? 127 : (qi < -127 ? -127 : qi);
            q[j] = qi;
        }
        o[i] = pack4(q[0], q[1], q[2], q[3]);
    }
    *(i32x4*)(xb + (size_t)row * Kd + t * 16) = o;
    if (t == 0) xs[row] = amax * (1.0f / 127.0f);
}

// ---------- 256x256 i8 GEMM, REG-STAGED (L2-allocating loads), 1 barrier/tile ----------
// C[m,n] = sw[n]*xs[m] * sum_k xq[m,k]*w8[n,k] + bias[n]
// r5 geometry: 8 waves = 2M x 4N, per-wave 128x64 out, BK=128, LDS 128 KiB
// (2 slots x {A,B} x 2 regions x [128][128]). Same read phases / register-
// cached frags / XOR swizzle as r5. CHANGE: staging is plain
// global_load_dwordx4 -> regs (allocates L2; panel sharers on one XCD can
// hit) issued at tile START (full-tile latency cover), then vmcnt(0) +
// 8x ds_write_b128 (swizzled addr) + lgkm0 at tile END. Writes target the
// OTHER slot, whose last reads are >=1 barrier old -> ONE barrier per tile.

#define BARRIER() asm volatile("s_barrier" ::: "memory")

#define LGKM0_FENCE() do {                                                     \
    asm volatile("s_waitcnt lgkmcnt(0)");                                      \
    __builtin_amdgcn_sched_barrier(0);                                         \
} while (0)

#define VMCNT(n) do {                                                          \
    asm volatile("s_waitcnt vmcnt(" #n ")" ::: "memory");                      \
    __builtin_amdgcn_sched_barrier(0);                                         \
} while (0)

// 8 coalesced dwordx4: A regions (h=i>>1, part=i&1) + B regions (j, part)
#define LOADG8(t) do {                                                         \
    _Pragma("unroll")                                                          \
    for (int i = 0; i < 4; ++i)                                                \
        sA[i] = *(const i32x4*)(Ab +                                           \
            (size_t)(gm0 + (i >> 1) * 64 + (i & 1) * 128 + qrow) * Kd          \
            + (t) * BK + gc16);                                                \
    _Pragma("unroll")                                                          \
    for (int i = 0; i < 4; ++i)                                                \
        sB[i] = *(const i32x4*)(Bw +                                           \
            (size_t)(gn0 + (i >> 1) * 32 + (i & 1) * 128 + bQ) * Kd            \
            + (t) * BK + gc16);                                                \
    __builtin_amdgcn_sched_barrier(0);                                         \
} while (0)

// mirror of r5's gload_lds destinations, swizzle applied on the write addr
#define WRITEL8(slot) do {                                                     \
    _Pragma("unroll")                                                          \
    for (int i = 0; i < 4; ++i)                                                \
        *(i32x4*)(&LDS[slot][0][i >> 1][(i & 1) * 64 + qrow][swc]) = sA[i];    \
    _Pragma("unroll")                                                          \
    for (int i = 0; i < 4; ++i)                                                \
        *(i32x4*)(&LDS[slot][1][i >> 1][(i & 1) * 64 + qrow][swc]) = sB[i];    \
    __builtin_amdgcn_sched_barrier(0);                                         \
} while (0)

#define READ_A(dst, slot, h) do {                                              \
    const char* lA_ = &LDS[slot][0][h][0][0];                                  \
    _Pragma("unroll")                                                          \
    for (int mi = 0; mi < 4; ++mi)                                             \
        _Pragma("unroll")                                                      \
        for (int kk = 0; kk < 2; ++kk) {                                       \
            const int row_ = wm * 64 + mi * 16 + lr;                           \
            const int col_ = (l4 * 16 + kk * 64) ^ xorv;                       \
            dst[mi][kk] = *(const i32x4*)(lA_ + row_ * 128 + col_);            \
        }                                                                      \
} while (0)

#define READ_B(dst, slot, j) do {                                              \
    const char* lB_ = &LDS[slot][1][j][0][0];                                  \
    _Pragma("unroll")                                                          \
    for (int ni = 0; ni < 2; ++ni)                                             \
        _Pragma("unroll")                                                      \
        for (int kk = 0; kk < 2; ++kk) {                                       \
            const int row_ = wn * 32 + ni * 16 + lr;                           \
            const int col_ = (l4 * 16 + kk * 64) ^ xorv;                       \
            dst[ni][kk] = *(const i32x4*)(lB_ + row_ * 128 + col_);            \
        }                                                                      \
} while (0)

#define MFMA_QUAD(h, j, AF, BF) do {                                           \
    __builtin_amdgcn_s_setprio(1);                                             \
    _Pragma("unroll")                                                          \
    for (int mi = 0; mi < 4; ++mi)                                             \
        _Pragma("unroll")                                                      \
        for (int ni = 0; ni < 2; ++ni)                                         \
            _Pragma("unroll")                                                  \
            for (int kk = 0; kk < 2; ++kk)                                     \
                acc[(h) * 4 + mi][(j) * 2 + ni] =                              \
                    __builtin_amdgcn_mfma_i32_16x16x64_i8(                     \
                        AF[mi][kk], BF[ni][kk],                                \
                        acc[(h) * 4 + mi][(j) * 2 + ni], 0, 0, 0);             \
    __builtin_amdgcn_s_setprio(0);                                             \
} while (0)

#define TILE(slot, oslot, t) do {                                              \
    i32x4 afA[4][2], afB[4][2], bfA[2][2], bfB[2][2];                          \
    if ((t) + 1 < NT) LOADG8((t) + 1);   /* coalesced, covers whole tile */    \
    READ_A(afA, slot, 0);                                                      \
    READ_B(bfA, slot, 0);                                                      \
    LGKM0_FENCE();                                                             \
    MFMA_QUAD(0, 0, afA, bfA);                                                 \
    READ_B(bfB, slot, 1);                                                      \
    LGKM0_FENCE();                                                             \
    MFMA_QUAD(0, 1, afA, bfB);                                                 \
    READ_A(afB, slot, 1);                                                      \
    LGKM0_FENCE();                                                             \
    MFMA_QUAD(1, 0, afB, bfA);                                                 \
    MFMA_QUAD(1, 1, afB, bfB);                                                 \
    if ((t) + 1 < NT) {                                                        \
        VMCNT(0);                        /* stage data arrived */              \
        WRITEL8(oslot);                  /* oslot: last read >=1 barrier ago */\
        LGKM0_FENCE();                   /* writes visible before barrier */   \
    }                                                                          \
    BARRIER();                           /* publishes oslot for tile t+1 */    \
} while (0)

__global__ __launch_bounds__(512, 2) void gemm8_kernel(
    const char* __restrict__ Ab,        // xq [M][K] i8
    const char* __restrict__ Bw,        // w8 [N][K] i8 (linear)
    const float* __restrict__ sw,       // per-n weight scale
    const float* __restrict__ xs,       // per-m activation scale
    const float* __restrict__ bias,
    float* __restrict__ C) {

    __shared__ __align__(16) char LDS[2][2][2][128][128];   // 128 KiB

    const int tid = threadIdx.x;
    const int l   = tid & 63;
    const int w   = tid >> 6;          // wave 0..7
    const int wm  = w >> 2;            // 0..1
    const int wn  = w & 3;             // 0..3
    const int lr  = l & 15;
    const int l4  = l >> 4;            // 0..3
    const int xorv = (lr & 7) << 4;

    // bijective XCD swizzle (256 wg, 32/XCD), m-fastest work order
    const int orig = blockIdx.x;
    const int work = (orig & 7) * 32 + (orig >> 3);
    const int gm0 = (work & 3) * 256;
    const int gn0 = (work >> 2) * 256;

    // staging geometry (coalesced source; swizzle applied on LDS write)
    const int qrow = w * 8 + (l >> 3);                 // 0..63
    const int bQ   = (w >> 2) * 64 + (w & 3) * 8 + (l >> 3);
    const int gc16 = (l & 7) * 16;
    const int swc  = gc16 ^ ((l >> 3) << 4);           // (row&7)==l>>3

    i32x4 sA[4], sB[4];                // staging regs, 32 VGPR

    f32x4 accf; (void)accf;
    i32x4 acc[8][4];
    #pragma unroll
    for (int i = 0; i < 8; ++i)
        #pragma unroll
        for (int j = 0; j < 4; ++j) {
            i32x4 z = {0, 0, 0, 0};
            acc[i][j] = z;
        }

    // prologue: tile 0 loaded + written
    LOADG8(0);
    VMCNT(0);
    WRITEL8(0);
    LGKM0_FENCE();
    BARRIER();

    #pragma unroll 1
    for (int tt = 0; tt < NT / 2; ++tt) {
        TILE(0, 1, 2 * tt);
        TILE(1, 0, 2 * tt + 1);
    }

    // epilogue: C = sw[n]*xs[m]*acc + bias[n]
    // C/D layout (dtype-independent): col = lane&15 (n), row = (lane>>4)*4+reg
    #pragma unroll
    for (int bj = 0; bj < 4; ++bj) {
        const int gn = gn0 + wn * 64 + bj * 16 + lr;
        const float sc = sw[gn];
        const float bi = bias[gn];
        #pragma unroll
        for (int ai = 0; ai < 8; ++ai) {
            const int gm = gm0 + wm * 128 + ai * 16 + l4 * 4;
            #pragma unroll
            for (int r = 0; r < 4; ++r)
                C[(size_t)(gm + r) * Nd + gn] =
                    (float)acc[ai][bj][r] * (sc * xs[gm + r]) + bi;
        }
    }
}

// ---------- fallback (ws too small): slow but correct ----------

__global__ __launch_bounds__(256) void naive_kernel(
    const float* __restrict__ x, const int* __restrict__ wq,
    const float* __restrict__ scale, const float* __restrict__ bias,
    float* __restrict__ out) {
    const int n = blockIdx.x * 256 + threadIdx.x;
    const int m = blockIdx.y;
    if (n >= Nd) return;
    const float* xr = x + (size_t)m * Kd;
    const int*   wr = wq + (size_t)n * Kd;
    float s = 0.f;
    for (int k = 0; k < Kd; ++k) s += xr[k] * (float)wr[k];
    out[(size_t)m * Nd + n] = s * scale[n] + bias[n];
}

// ---------- launch ----------

extern "C" void kernel_launch(void* const* d_in, const int* in_sizes, int n_in,
                              void* d_out, int out_size, void* d_ws, size_t ws_size,
                              hipStream_t stream) {
    const float* x     = (const float*)d_in[0];
    const int*   wq    = (const int*)d_in[1];
    const float* scale = (const float*)d_in[2];
    const float* bias  = (const float*)d_in[3];
    float* out = (float*)d_out;

    const size_t w_bytes = (size_t)Nd * Kd;              // 64 MiB (i8)
    const size_t x_bytes = (size_t)Md * Kd;              //  4 MiB (i8)
    const size_t s_bytes = (size_t)Md * sizeof(float);   //  4 KiB
    if (ws_size >= w_bytes + x_bytes + s_bytes && d_ws != nullptr) {
        char*  wb = (char*)d_ws;
        char*  xb = wb + w_bytes;
        float* xs = (float*)(xb + x_bytes);
        convert_w_kernel<<<4096, 256, 0, stream>>>(wq, wb);
        convert_x_kernel<<<Md, 256, 0, stream>>>(x, xb, xs);
        gemm8_kernel<<<256, 512, 0, stream>>>(xb, wb, scale, xs, bias, out);
    } else {
        dim3 grid(Nd / 256, Md);
        naive_kernel<<<grid, 256, 0, stream>>>(x, wq, scale, bias, out);
    }
}

// Round 12
// 147.455 us; speedup vs baseline: 3.3896x; 1.1715x over previous
//
#include <hip/hip_runtime.h>

typedef __attribute__((ext_vector_type(4))) float f32x4;
typedef __attribute__((ext_vector_type(4))) int   i32x4;

static constexpr int Kd = 4096, Nd = 16384, Md = 1024;
static constexpr int BK = 128;          // K-elems (i8) per tile
static constexpr int NT = Kd / BK;      // 32 K-tiles

// ---------- helpers ----------

__device__ __forceinline__ void gload16(const char* g, char* l) {
    __builtin_amdgcn_global_load_lds(
        (const __attribute__((address_space(1))) void*)g,
        (__attribute__((address_space(3))) void*)l, 16, 0, 0);
}

__device__ __forceinline__ int pack4(int a, int b, int c, int d) {
    return (a & 255) | ((b & 255) << 8) | ((c & 255) << 16) | (d << 24);
}

// ---------- convert W: int32 [N][K] -> i8 in FRAG-DIRECT layout (r6) ----------
// chunk c (16 B) = (((nt*32+kt)*4+wn)*8+fid)*64 + l, fid = j*4+ni*2+kk.
// Holds W[n = nt*256+wn*64+j*32+ni*16+(l&15)][k = kt*128+kk*64+(l>>4)*16 .. +16)

__global__ __launch_bounds__(256) void convert_w_kernel(
    const int* __restrict__ wq, char* __restrict__ wb) {
    const int total = (Nd / 256) * NT * 4 * 8 * 64;   // 4,194,304 chunks
    int c = blockIdx.x * 256 + threadIdx.x;
    const int stride = gridDim.x * 256;
    for (; c < total; c += stride) {
        const int l   = c & 63;
        const int fid = (c >> 6) & 7;
        const int wn  = (c >> 9) & 3;
        const int kt  = (c >> 11) & 31;
        const int nt  = c >> 16;
        const int j   = fid >> 2, ni = (fid >> 1) & 1, kkb = fid & 1;
        const int lr  = l & 15,   l4 = l >> 4;
        const int n   = nt * 256 + wn * 64 + j * 32 + ni * 16 + lr;
        const int k0  = kt * 128 + kkb * 64 + l4 * 16;
        const int* src = wq + (size_t)n * Kd + k0;
        i32x4 a = *(const i32x4*)(src);
        i32x4 b = *(const i32x4*)(src + 4);
        i32x4 cc = *(const i32x4*)(src + 8);
        i32x4 d = *(const i32x4*)(src + 12);
        i32x4 o;
        o[0] = pack4(a[0], a[1], a[2], a[3]);
        o[1] = pack4(b[0], b[1], b[2], b[3]);
        o[2] = pack4(cc[0], cc[1], cc[2], cc[3]);
        o[3] = pack4(d[0], d[1], d[2], d[3]);
        *((i32x4*)wb + c) = o;
    }
}

// ---------- convert X: f32 [M][K] -> per-row absmax-scaled int8 ----------

__global__ __launch_bounds__(256) void convert_x_kernel(
    const float* __restrict__ x, char* __restrict__ xb, float* __restrict__ xs) {
    const int row = blockIdx.x;
    const int t   = threadIdx.x;
    const float* xr = x + (size_t)row * Kd;

    f32x4 v[4];
    float amax = 0.f;
    #pragma unroll
    for (int i = 0; i < 4; ++i) {
        v[i] = *(const f32x4*)(xr + t * 16 + i * 4);
        #pragma unroll
        for (int j = 0; j < 4; ++j) amax = fmaxf(amax, fabsf(v[i][j]));
    }
    #pragma unroll
    for (int off = 32; off; off >>= 1)
        amax = fmaxf(amax, __shfl_xor(amax, off));
    __shared__ float wmax[4];
    if ((t & 63) == 0) wmax[t >> 6] = amax;
    __syncthreads();
    amax = fmaxf(fmaxf(wmax[0], wmax[1]), fmaxf(wmax[2], wmax[3]));
    amax = fmaxf(amax, 1e-20f);

    const float inv = 127.0f / amax;
    i32x4 o;
    #pragma unroll
    for (int i = 0; i < 4; ++i) {
        int q[4];
        #pragma unroll
        for (int j = 0; j < 4; ++j) {
            int qi = __float2int_rn(v[i][j] * inv);
            qi = qi > 127 ? 127 : (qi < -127 ? -127 : qi);
            q[j] = qi;
        }
        o[i] = pack4(q[0], q[1], q[2], q[3]);
    }
    *(i32x4*)(xb + (size_t)row * Kd + t * 16) = o;
    if (t == 0) xs[row] = amax * (1.0f / 127.0f);
}

// ---------- 256x256 i8 GEMM: A via LDS, B frag-direct, DEEP B prefetch ----------
// C[m,n] = sw[n]*xs[m] * sum_k xq[m,k]*w8[n,k] + bias[n]
// r6 structure; ONE change: BOTH B j-half loads for tile t+1 issue at the
// START of tile t (in-flight ~ full tile >> 900-cyc HBM first-touch miss).
// bf0 AND bf1 ping-pong (64 regs B). 8 waves = 2M x 4N; per-wave 128x64.
// A: i8 via LDS (2 slots x 16 KiB, XOR swizzle, gload_lds, 2/thread/tile).
// Per-tile FIFO ledger (oldest left; issue order A then B):
//  entry [B(t):8] ; issue A(t+1):2, B(t+1):8 -> 18 in flight ;
//  READ_A(af,0) ; VMCNT(10) -> B(t) retired ; LGKM0 ; Q(0,0) Q(0,1) ;
//  READ_A(af,1) ; LGKM0 ; Q(1,0) Q(1,1) ;
//  VMCNT(8) -> A(t+1) in LDS (A issued before B) ; BARRIER.
// Tail t=NT-1: no issues, VMCNT(0), no end wait/barrier.

#define BARRIER() asm volatile("s_barrier" ::: "memory")

#define LGKM0_FENCE() do {                                                     \
    asm volatile("s_waitcnt lgkmcnt(0)");                                      \
    __builtin_amdgcn_sched_barrier(0);                                         \
} while (0)

#define VMCNT(n) do {                                                          \
    asm volatile("s_waitcnt vmcnt(" #n ")" ::: "memory");                      \
    __builtin_amdgcn_sched_barrier(0);                                         \
} while (0)

#define STAGE_AFULL(slot, kt) do {                                             \
    _Pragma("unroll")                                                          \
    for (int h_ = 0; h_ < 2; ++h_) {                                           \
        char* lb_ = &LDSA[slot][h_][w * 8][0];                                 \
        gload16(Ab + (aRow0 + h_ * 64) * (size_t)Kd + (kt) * BK + gcol, lb_);  \
        gload16(Ab + (aRow0 + h_ * 64 + 128) * (size_t)Kd + (kt) * BK + gcol,  \
                lb_ + 64 * 128);                                               \
    }                                                                          \
    __builtin_amdgcn_sched_barrier(0);                                         \
} while (0)

#define LOAD_BF(buf, kt, jj) do {                                              \
    const i32x4* p_ = Bfr + (size_t)(kt) * 2048 + wn * 512 + (jj) * 256 + l;   \
    buf[0][0] = p_[0];                                                         \
    buf[0][1] = p_[64];                                                        \
    buf[1][0] = p_[128];                                                       \
    buf[1][1] = p_[192];                                                       \
    __builtin_amdgcn_sched_barrier(0);                                         \
} while (0)

#define READ_A(dst, slot, h) do {                                              \
    const char* lA_ = &LDSA[slot][h][0][0];                                    \
    _Pragma("unroll")                                                          \
    for (int mi = 0; mi < 4; ++mi)                                             \
        _Pragma("unroll")                                                      \
        for (int kk = 0; kk < 2; ++kk) {                                       \
            const int row_ = wm * 64 + mi * 16 + lr;                           \
            const int col_ = (l4 * 16 + kk * 64) ^ xorv;                       \
            dst[mi][kk] = *(const i32x4*)(lA_ + row_ * 128 + col_);            \
        }                                                                      \
    __builtin_amdgcn_sched_barrier(0);                                         \
} while (0)

#define MFMA_QUAD(h, j, AF, BF) do {                                           \
    __builtin_amdgcn_s_setprio(1);                                             \
    _Pragma("unroll")                                                          \
    for (int mi = 0; mi < 4; ++mi)                                             \
        _Pragma("unroll")                                                      \
        for (int ni = 0; ni < 2; ++ni)                                         \
            _Pragma("unroll")                                                  \
            for (int kk = 0; kk < 2; ++kk)                                     \
                acc[(h) * 4 + mi][(j) * 2 + ni] =                              \
                    __builtin_amdgcn_mfma_i32_16x16x64_i8(                     \
                        AF[mi][kk], BF[ni][kk],                                \
                        acc[(h) * 4 + mi][(j) * 2 + ni], 0, 0, 0);             \
    __builtin_amdgcn_s_setprio(0);                                             \
} while (0)

#define TILE(slot, oslot, BF0C, BF1C, BF0N, BF1N, t) do {                      \
    if ((t) + 1 < NT) {                                                        \
        STAGE_AFULL(oslot, (t) + 1);   /* ops 1-2 (A first!) */                \
        LOAD_BF(BF0N, (t) + 1, 0);     /* ops 3-6 */                           \
        LOAD_BF(BF1N, (t) + 1, 1);     /* ops 7-10 */                          \
    }                                                                          \
    READ_A(af, slot, 0);                                                       \
    if ((t) + 1 < NT) { VMCNT(10); } else { VMCNT(0); }  /* B(t) retired */    \
    LGKM0_FENCE();                                                             \
    MFMA_QUAD(0, 0, af, BF0C);                                                 \
    MFMA_QUAD(0, 1, af, BF1C);                                                 \
    READ_A(af, slot, 1);                                                       \
    LGKM0_FENCE();                                                             \
    MFMA_QUAD(1, 0, af, BF0C);                                                 \
    MFMA_QUAD(1, 1, af, BF1C);                                                 \
    if ((t) + 1 < NT) { VMCNT(8); BARRIER(); }   /* A(t+1) in LDS */           \
} while (0)

__global__ __launch_bounds__(512, 2) void gemm8_kernel(
    const char* __restrict__ Ab,        // xq [M][K] i8
    const char* __restrict__ Bw,        // wq frag-direct i8 (64 MiB)
    const float* __restrict__ sw,       // per-n weight scale
    const float* __restrict__ xs,       // per-m activation scale
    const float* __restrict__ bias,
    float* __restrict__ C) {

    __shared__ __align__(16) char LDSA[2][2][128][128];   // 64 KiB, A only

    const int tid = threadIdx.x;
    const int l   = tid & 63;
    const int w   = tid >> 6;          // wave 0..7
    const int wm  = w >> 2;            // 0..1 (m half)
    const int wn  = w & 3;             // 0..3 (n quarter)
    const int lr  = l & 15;
    const int l4  = l >> 4;            // 0..3
    const int xorv = (lr & 7) << 4;

    // bijective XCD swizzle (256 wg, 32/XCD), m-fastest work order
    const int orig = blockIdx.x;
    const int work = (orig & 7) * 32 + (orig >> 3);
    const int gm0 = (work & 3) * 256;
    const int gn0 = (work >> 2) * 256;

    // A staging source geometry (inverse of read-side XOR swizzle), bytes
    const int g_log = (l & 7) ^ ((l >> 3) & 7);
    const int gcol  = g_log * 16;
    const size_t aRow0 = (size_t)(gm0 + w * 8 + (l >> 3));

    // B frag-direct base for this block's n-tile
    const i32x4* Bfr = (const i32x4*)Bw + (size_t)(work >> 2) * 65536;

    i32x4 af[4][2];                    // A frags, 32 regs (reused h=0/1)
    i32x4 bf0a[2][2], bf0b[2][2];      // j=0 frags ping-pong, 32 regs
    i32x4 bf1a[2][2], bf1b[2][2];      // j=1 frags ping-pong, 32 regs

    i32x4 acc[8][4];                   // 128 regs
    #pragma unroll
    for (int i = 0; i < 8; ++i)
        #pragma unroll
        for (int j = 0; j < 4; ++j) {
            i32x4 z = {0, 0, 0, 0};
            acc[i][j] = z;
        }

    // prologue: A(0) staged, B(0) both halves issued
    STAGE_AFULL(0, 0);                 // ops 1-2
    LOAD_BF(bf0a, 0, 0);               // ops 3-6
    LOAD_BF(bf1a, 0, 1);               // ops 7-10
    VMCNT(8);                          // A(0) in LDS; B(0):8 in flight
    BARRIER();

    #pragma unroll 1
    for (int tt = 0; tt < NT / 2; ++tt) {
        TILE(0, 1, bf0a, bf1a, bf0b, bf1b, 2 * tt);
        TILE(1, 0, bf0b, bf1b, bf0a, bf1a, 2 * tt + 1);
    }

    // epilogue: C = sw[n]*xs[m]*acc + bias[n]
    // C/D layout (dtype-independent): col = lane&15 (n), row = (lane>>4)*4+reg
    #pragma unroll
    for (int bj = 0; bj < 4; ++bj) {
        const int gn = gn0 + wn * 64 + bj * 16 + lr;
        const float sc = sw[gn];
        const float bi = bias[gn];
        #pragma unroll
        for (int ai = 0; ai < 8; ++ai) {
            const int gm = gm0 + wm * 128 + ai * 16 + l4 * 4;
            #pragma unroll
            for (int r = 0; r < 4; ++r)
                C[(size_t)(gm + r) * Nd + gn] =
                    (float)acc[ai][bj][r] * (sc * xs[gm + r]) + bi;
        }
    }
}

// ---------- fallback (ws too small): slow but correct ----------

__global__ __launch_bounds__(256) void naive_kernel(
    const float* __restrict__ x, const int* __restrict__ wq,
    const float* __restrict__ scale, const float* __restrict__ bias,
    float* __restrict__ out) {
    const int n = blockIdx.x * 256 + threadIdx.x;
    const int m = blockIdx.y;
    if (n >= Nd) return;
    const float* xr = x + (size_t)m * Kd;
    const int*   wr = wq + (size_t)n * Kd;
    float s = 0.f;
    for (int k = 0; k < Kd; ++k) s += xr[k] * (float)wr[k];
    out[(size_t)m * Nd + n] = s * scale[n] + bias[n];
}

// ---------- launch ----------

extern "C" void kernel_launch(void* const* d_in, const int* in_sizes, int n_in,
                              void* d_out, int out_size, void* d_ws, size_t ws_size,
                              hipStream_t stream) {
    const float* x     = (const float*)d_in[0];
    const int*   wq    = (const int*)d_in[1];
    const float* scale = (const float*)d_in[2];
    const float* bias  = (const float*)d_in[3];
    float* out = (float*)d_out;

    const size_t w_bytes = (size_t)Nd * Kd;              // 64 MiB (i8)
    const size_t x_bytes = (size_t)Md * Kd;              //  4 MiB (i8)
    const size_t s_bytes = (size_t)Md * sizeof(float);   //  4 KiB
    if (ws_size >= w_bytes + x_bytes + s_bytes && d_ws != nullptr) {
        char*  wb = (char*)d_ws;
        char*  xb = wb + w_bytes;
        float* xs = (float*)(xb + x_bytes);
        convert_w_kernel<<<8192, 256, 0, stream>>>(wq, wb);
        convert_x_kernel<<<Md, 256, 0, stream>>>(x, xb, xs);
        gemm8_kernel<<<256, 512, 0, stream>>>(xb, wb, scale, xs, bias, out);
    } else {
        dim3 grid(Nd / 256, Md);
        naive_kernel<<<grid, 256, 0, stream>>>(x, wq, scale, bias, out);
    }
}